// Round 1
// baseline (313.985 us; speedup 1.0000x reference)
//
#include <hip/hip_runtime.h>
#include <hip/hip_bf16.h>

// PointProp for MI355X (gfx950) — R5.
//   kP: prep (Wc = W0r@Wu@Wm folded via per-block LDS chain; bias chain in
//       block 132)  — replaces old kA-prep + kB, one less kernel boundary.
//   kC: pack weights to MFMA frag order (unchanged).
//   kD: FUSED comp-sum + 4-layer MLP. Each wave streams its own 16 rows of
//       components (8 k-slices, f32x4-pair coalesced, k-ascending add order ==
//       old kA bitwise), packs to bf16 cs[] regs, then runs the MLP exactly as
//       R4. Deletes the 67MB csum round-trip and hides MLP compute under the
//       537MB comp stream via 3-blocks/CU overlap. Non-temporal on read-once
//       streams + out stores to keep weight chunks in L2.
// Math: out = L4(relu(L3(relu(L2(relu(sig@W0s^T + csum@Wc^T + bias1))))))
// with Wc = W0r@Wu@Wm folded (linearity), H padded 132->160.

typedef float  f32x4  __attribute__((ext_vector_type(4)));
typedef __bf16 bf16x8 __attribute__((ext_vector_type(8)));
typedef unsigned int   u32x2 __attribute__((ext_vector_type(2)));
typedef unsigned short u16x8 __attribute__((ext_vector_type(8)));

__device__ __forceinline__ unsigned short f2bf(float f) {
  unsigned int u = __builtin_bit_cast(unsigned int, f);
  u += 0x7fffu + ((u >> 16) & 1u);   // RNE
  return (unsigned short)(u >> 16);
}

__device__ __forceinline__ u32x2 pack4(f32x4 v) {
  u32x2 r;
  r[0] = (unsigned)f2bf(v[0]) | ((unsigned)f2bf(v[1]) << 16);
  r[1] = (unsigned)f2bf(v[2]) | ((unsigned)f2bf(v[3]) << 16);
  return r;
}

// ---- async global->LDS (dest = wave-uniform base + lane*size) ----
__device__ __forceinline__ void gl16(const void* g, void* l) {
  __builtin_amdgcn_global_load_lds(
      (const __attribute__((address_space(1))) unsigned*)(unsigned long long)g,
      (__attribute__((address_space(3))) unsigned*)(unsigned)(unsigned long long)l,
      16, 0, 0);
}
__device__ __forceinline__ void gl4(const void* g, void* l) {
  __builtin_amdgcn_global_load_lds(
      (const __attribute__((address_space(1))) unsigned*)(unsigned long long)g,
      (__attribute__((address_space(3))) unsigned*)(unsigned)(unsigned long long)l,
      4, 0, 0);
}

// stage a 10KB chunk: 2x16B issues (8KB) + 2x4B issues (2KB)
__device__ __forceinline__ void stage10k(const char* src, char* dst,
                                         int wave, int lane) {
  const char* g0 = src + wave * 1024 + lane * 16;
  char* l0 = dst + wave * 1024;
  gl16(g0, l0);
  gl16(g0 + 4096, l0 + 4096);
  const char* g1 = src + 8192 + wave * 256 + lane * 4;
  char* l1 = dst + 8192 + wave * 256;
  gl4(g1, l1);
  gl4(g1 + 1024, l1 + 1024);
}
// stage a 6KB chunk: 1x16B issue (4KB) + 2x4B issues (2KB)
__device__ __forceinline__ void stage6k(const char* src, char* dst,
                                        int wave, int lane) {
  gl16(src + wave * 1024 + lane * 16, dst + wave * 1024);
  const char* g1 = src + 4096 + wave * 256 + lane * 4;
  char* l1 = dst + 4096 + wave * 256;
  gl4(g1, l1);
  gl4(g1 + 1024, l1 + 1024);
}

// ---------------- Kernel P: all prep (Wc, bias1, padded biases) -------------
// blocks 0..131: row h of Wc = (W0r@Wu)@Wm, chained through LDS.
// block 132: rb = 8*(Wu@bm)+bu (per-thread row dot, L1-friendly), then
//            bias1[t] = b0[t] + W0r[t,:]@rb, plus zero-padded b1p/b2p.
__global__ __launch_bounds__(256) void kP(
    const float* __restrict__ W0, const float* __restrict__ Wu,
    const float* __restrict__ Wm, const float* __restrict__ bm,
    const float* __restrict__ bu, const float* __restrict__ b0,
    const float* __restrict__ b1, const float* __restrict__ b2,
    float* __restrict__ Wc, float* __restrict__ bias1,
    float* __restrict__ b1p, float* __restrict__ b2p) {
  const int b = blockIdx.x;
  const int d = threadIdx.x;
  if (b < 132) {
    __shared__ float u[256];
    const int h = b;
    float s = 0.f;
#pragma unroll 8
    for (int i = 0; i < 256; ++i) s += W0[h * 512 + 256 + i] * Wu[i * 256 + d];
    u[d] = s;
    __syncthreads();
    float s2 = 0.f;
#pragma unroll 8
    for (int j = 0; j < 256; ++j) s2 += u[j] * Wm[j * 256 + d];
    Wc[h * 256 + d] = s2;
  } else {
    __shared__ float bml[256];
    __shared__ float rbl[256];
    bml[d] = bm[d];
    __syncthreads();
    // rb[d] = 8 * sum_i Wu[d,i]*bm[i] + bu[d]  (thread d walks its own row,
    // f32x4; lines stay hot in L1 across consecutive i)
    {
      const f32x4* wr = (const f32x4*)(Wu + d * 256);
      const f32x4* bm4 = (const f32x4*)bml;
      float s = 0.f;
#pragma unroll 8
      for (int i = 0; i < 64; ++i) {
        f32x4 w = wr[i], v = bm4[i];
        s += w[0] * v[0] + w[1] * v[1] + w[2] * v[2] + w[3] * v[3];
      }
      rbl[d] = 8.f * s + bu[d];
    }
    __syncthreads();
    if (d < 160) {
      float v = 0.f;
      if (d < 132) {
        float s = 0.f;
#pragma unroll 8
        for (int j = 0; j < 256; ++j) s += W0[d * 512 + 256 + j] * rbl[j];
        v = b0[d] + s;
      }
      bias1[d] = v;
      b1p[d] = (d < 132) ? b1[d] : 0.f;
      b2p[d] = (d < 132) ? b2[d] : 0.f;
    }
  }
}

// ---------------- Kernel C: pack weights to MFMA B-frag order (bf16) --------
// Chunk (kk,nt) = 1024B: lane l holds B[kk*32+(l>>4)*8+j][nt*16+(l&15)], j=0..7.
// L1: K=512,N=160; L2/L3: 160x160; L4: 160x256. P1..P4 CONTIGUOUS in ws.
__global__ __launch_bounds__(256) void kC(
    const float* __restrict__ W0, const float* __restrict__ Wc,
    const float* __restrict__ W1, const float* __restrict__ W2,
    const float* __restrict__ W3,
    unsigned short* __restrict__ P1, unsigned short* __restrict__ P2,
    unsigned short* __restrict__ P3, unsigned short* __restrict__ P4) {
  int e = blockIdx.x * 256 + threadIdx.x;
  if (e >= 174080) return;
  unsigned short* dst; int NT, rel, mode;
  if (e < 81920)       { dst = P1; NT = 10; rel = e;          mode = 0; }
  else if (e < 107520) { dst = P2; NT = 10; rel = e - 81920;  mode = 1; }
  else if (e < 133120) { dst = P3; NT = 10; rel = e - 107520; mode = 2; }
  else                 { dst = P4; NT = 16; rel = e - 133120; mode = 3; }
  int chunk = rel >> 9, q = rel & 511;
  int lane = q >> 3, j = q & 7;
  int kk = chunk / NT, nt = chunk - kk * NT;
  int k = kk * 32 + (lane >> 4) * 8 + j;
  int n = nt * 16 + (lane & 15);
  float v = 0.f;
  if (mode == 0) {
    if (n < 132) v = (k < 256) ? W0[n * 512 + k] : Wc[n * 256 + (k - 256)];
  } else if (mode == 1) {
    if (n < 132 && k < 132) v = W1[n * 132 + k];
  } else if (mode == 2) {
    if (n < 132 && k < 132) v = W2[n * 132 + k];
  } else {
    if (k < 132) v = W3[n * 132 + k];
  }
  dst[rel] = f2bf(v);
}

// ---------------- Kernel D: fused comp-sum + 4-layer MLP --------------------
// grid 1024 x 256; wave owns 16 rows. LDS 53248B: 4 per-wave act tiles
// [16 rows][512B] XOR-swizzled (32KB) + weight dbuf 2x10KB.
// Phase 0: signal->act, issue weight chunk0 stage, stream 16x8x1KB of comp
// into regs (k-ascending add order == old kA), pack to cs[8] bf16.
// Then: K-split layer 1 (signal half, then cs half), 2 hidden layers, L4.
__global__ __launch_bounds__(256, 3) void kD(
    const float* __restrict__ signal, const float* __restrict__ comp,
    const unsigned short* __restrict__ Pseq,
    const float* __restrict__ bias1, const float* __restrict__ b1p,
    const float* __restrict__ b2p, const float* __restrict__ b3,
    float* __restrict__ out) {
  extern __shared__ char lds[];
  const int tid = threadIdx.x;
  const int wave = tid >> 6;
  const int lane = tid & 63;
  const int lhalf = lane >> 4;
  const int l16 = lane & 15;
  char* act = lds + wave * 8192;
  char* wbA = lds + 32768;
  char* wbB = lds + 32768 + 10240;
  const char* Pb = (const char*)Pseq;
  const int row0 = ((int)blockIdx.x * 4 + wave) * 16;
  const int asw = (l16 & 7) << 4;

  // ---- signal: load 16 rows f32, pack -> act tile (cols 0..255 bf16) ----
  f32x4 sg[16];
  const f32x4* sp = (const f32x4*)signal;
#pragma unroll
  for (int r = 0; r < 16; ++r)
    sg[r] = __builtin_nontemporal_load(sp + (size_t)(row0 + r) * 64 + lane);
#pragma unroll
  for (int r = 0; r < 16; ++r)
    *(u32x2*)(act + r * 512 + ((lane * 8) ^ ((r & 7) << 4))) = pack4(sg[r]);

  stage10k(Pb, wbA, wave, lane);   // L1 chunk 0 -> buf0 (async; overlaps below)

  // ---- fused comp-sum -> cs[8] regs (same layout old kD loaded from csum:
  //      lane (r2=lane>>5, c32=lane&31) holds rows {2j+r2}, cols c32*8..+7) ----
  const int r2 = lane >> 5, c32 = lane & 31;
  u16x8 cs[8];
  const f32x4* cp = (const f32x4*)comp;
#pragma unroll
  for (int g = 0; g < 2; ++g) {          // 2 groups of 4 row-pairs: caps VGPRs
    f32x4 a0[4], a1[4];
#pragma unroll
    for (int j = 0; j < 4; ++j) {
      const size_t ix = (size_t)(row0 + 2 * (g * 4 + j) + r2) * 64 + c32 * 2;
      a0[j] = __builtin_nontemporal_load(cp + ix);
      a1[j] = __builtin_nontemporal_load(cp + ix + 1);
    }
#pragma unroll
    for (int k = 1; k < 8; ++k) {
      f32x4 t0[4], t1[4];
#pragma unroll
      for (int j = 0; j < 4; ++j) {
        const size_t ix = (size_t)k * 4194304u +
                          (size_t)(row0 + 2 * (g * 4 + j) + r2) * 64 + c32 * 2;
        t0[j] = __builtin_nontemporal_load(cp + ix);
        t1[j] = __builtin_nontemporal_load(cp + ix + 1);
      }
#pragma unroll
      for (int j = 0; j < 4; ++j) { a0[j] += t0[j]; a1[j] += t1[j]; }
    }
#pragma unroll
    for (int j = 0; j < 4; ++j) {
      u16x8 v;
      v[0] = f2bf(a0[j][0]); v[1] = f2bf(a0[j][1]);
      v[2] = f2bf(a0[j][2]); v[3] = f2bf(a0[j][3]);
      v[4] = f2bf(a1[j][0]); v[5] = f2bf(a1[j][1]);
      v[6] = f2bf(a1[j][2]); v[7] = f2bf(a1[j][3]);
      cs[g * 4 + j] = v;
    }
  }
  __syncthreads();

  f32x4 acc[10];
#pragma unroll
  for (int i = 0; i < 10; ++i) acc[i] = f32x4{0.f, 0.f, 0.f, 0.f};

  // ---- layer 1 pass 1 (signal half), chunks 0..7 ----
#pragma unroll
  for (int kk = 0; kk < 8; ++kk) {
    stage10k(Pb + (kk + 1) * 10240, (((kk + 1) & 1) ? wbB : wbA), wave, lane);
    char* wb = (kk & 1) ? wbB : wbA;
    bf16x8 af = *(const bf16x8*)(act + l16 * 512 + ((kk * 64 + lhalf * 16) ^ asw));
#pragma unroll
    for (int nt = 0; nt < 10; ++nt)
      acc[nt] = __builtin_amdgcn_mfma_f32_16x16x32_bf16(
          af, *(const bf16x8*)(wb + nt * 1024 + lane * 16), acc[nt], 0, 0, 0);
    __syncthreads();
  }

  // overwrite act tile with comp-sum (wave-local)
  asm volatile("" ::: "memory");
#pragma unroll
  for (int j = 0; j < 8; ++j) {
    const int rw = 2 * j + r2;
    *(u16x8*)(act + rw * 512 + ((c32 * 16) ^ ((rw & 7) << 4))) = cs[j];
  }
  asm volatile("" ::: "memory");

  // ---- layer 1 pass 2 (comp-sum half), chunks 8..15 ----
#pragma unroll
  for (int kk = 8; kk < 16; ++kk) {
    if (kk < 15)
      stage10k(Pb + (kk + 1) * 10240, (((kk + 1) & 1) ? wbB : wbA), wave, lane);
    else
      stage10k(Pb + 163840, wbA, wave, lane);          // L2 chunk0 (c=16, buf0)
    char* wb = (kk & 1) ? wbB : wbA;
    bf16x8 af =
        *(const bf16x8*)(act + l16 * 512 + (((kk - 8) * 64 + lhalf * 16) ^ asw));
#pragma unroll
    for (int nt = 0; nt < 10; ++nt)
      acc[nt] = __builtin_amdgcn_mfma_f32_16x16x32_bf16(
          af, *(const bf16x8*)(wb + nt * 1024 + lane * 16), acc[nt], 0, 0, 0);
    __syncthreads();
  }

  // bias + relu -> act
  {
    float bv[10];
#pragma unroll
    for (int nt = 0; nt < 10; ++nt) bv[nt] = bias1[nt * 16 + l16];
    asm volatile("" ::: "memory");
#pragma unroll
    for (int nt = 0; nt < 10; ++nt) {
#pragma unroll
      for (int r = 0; r < 4; ++r) {
        const int row = lhalf * 4 + r;
        float v = fmaxf(acc[nt][r] + bv[nt], 0.f);
        *(unsigned short*)(act + row * 512 +
                           (((nt * 16 + l16) * 2) ^ ((row & 7) << 4))) = f2bf(v);
      }
    }
    asm volatile("" ::: "memory");
  }

  // ---- hidden layers (L=0: W1 @ Pb+163840; L=1: W2 @ Pb+215040) ----
#pragma unroll
  for (int L = 0; L < 2; ++L) {
    const char* hb = Pb + (L ? 215040 : 163840);
    const float* hbias = L ? b2p : b1p;
#pragma unroll
    for (int i = 0; i < 10; ++i) acc[i] = f32x4{0.f, 0.f, 0.f, 0.f};
#pragma unroll
    for (int kk = 0; kk < 5; ++kk) {
      // chunk counter c: L=0 -> 16+kk, L=1 -> 21+kk; parity = (kk+L)&1
      const char* nsrc = (kk < 4) ? (hb + (kk + 1) * 10240)
                                  : (L ? (Pb + 266240) : (Pb + 215040));
      stage10k(nsrc, (((kk + L + 1) & 1) ? wbB : wbA), wave, lane);
      char* wb = ((kk + L) & 1) ? wbB : wbA;
      bf16x8 af =
          *(const bf16x8*)(act + l16 * 512 + ((kk * 64 + lhalf * 16) ^ asw));
#pragma unroll
      for (int nt = 0; nt < 10; ++nt)
        acc[nt] = __builtin_amdgcn_mfma_f32_16x16x32_bf16(
            af, *(const bf16x8*)(wb + nt * 1024 + lane * 16), acc[nt], 0, 0, 0);
      __syncthreads();
    }
    float bv[10];
#pragma unroll
    for (int nt = 0; nt < 10; ++nt) bv[nt] = hbias[nt * 16 + l16];
    asm volatile("" ::: "memory");
#pragma unroll
    for (int nt = 0; nt < 10; ++nt) {
#pragma unroll
      for (int r = 0; r < 4; ++r) {
        const int row = lhalf * 4 + r;
        float v = fmaxf(acc[nt][r] + bv[nt], 0.f);
        *(unsigned short*)(act + row * 512 +
                           (((nt * 16 + l16) * 2) ^ ((row & 7) << 4))) = f2bf(v);
      }
    }
    asm volatile("" ::: "memory");
  }

  // ---- layer 4: chunks (kk,h0)=nt0..9 @buf0, (kk,h1)=nt10..15 @buf1 ----
  f32x4 a4[16];
#pragma unroll
  for (int i = 0; i < 16; ++i) a4[i] = f32x4{0.f, 0.f, 0.f, 0.f};
  const char* P4b = Pb + 266240;
#pragma unroll
  for (int kk = 0; kk < 5; ++kk) {
    // h0 phase
    stage6k(P4b + kk * 16384 + 10240, wbB, wave, lane);
    bf16x8 af =
        *(const bf16x8*)(act + l16 * 512 + ((kk * 64 + lhalf * 16) ^ asw));
#pragma unroll
    for (int nt = 0; nt < 10; ++nt)
      a4[nt] = __builtin_amdgcn_mfma_f32_16x16x32_bf16(
          af, *(const bf16x8*)(wbA + nt * 1024 + lane * 16), a4[nt], 0, 0, 0);
    __syncthreads();
    // h1 phase
    if (kk < 4) stage10k(P4b + (kk + 1) * 16384, wbA, wave, lane);
#pragma unroll
    for (int nt = 10; nt < 16; ++nt)
      a4[nt] = __builtin_amdgcn_mfma_f32_16x16x32_bf16(
          af, *(const bf16x8*)(wbB + (nt - 10) * 1024 + lane * 16), a4[nt], 0, 0, 0);
    __syncthreads();
  }

  // ---- store (non-temporal: write-once stream) ----
  float bv[16];
#pragma unroll
  for (int nt = 0; nt < 16; ++nt) bv[nt] = b3[nt * 16 + l16];
  float* op = out + (size_t)(row0 + lhalf * 4) * 256 + l16;
#pragma unroll
  for (int nt = 0; nt < 16; ++nt) {
#pragma unroll
    for (int r = 0; r < 4; ++r)
      __builtin_nontemporal_store(a4[nt][r] + bv[nt],
                                  op + (size_t)r * 256 + nt * 16);
  }
}

// ---------------- launcher ----------------
extern "C" void kernel_launch(void* const* d_in, const int* in_sizes, int n_in,
                              void* d_out, int out_size, void* d_ws, size_t ws_size,
                              hipStream_t stream) {
  const float* signal = (const float*)d_in[0];
  const float* comp   = (const float*)d_in[1];
  const float* Wm = (const float*)d_in[2];
  const float* bm = (const float*)d_in[3];
  const float* Wu = (const float*)d_in[4];
  const float* bu = (const float*)d_in[5];
  const float* W0 = (const float*)d_in[6];
  const float* b0 = (const float*)d_in[7];
  const float* W1 = (const float*)d_in[8];
  const float* b1 = (const float*)d_in[9];
  const float* W2 = (const float*)d_in[10];
  const float* b2 = (const float*)d_in[11];
  const float* W3 = (const float*)d_in[12];
  const float* b3 = (const float*)d_in[13];

  char* ws = (char*)d_ws;
  float* Wc    = (float*)(ws + 0);        // 33792 f32 (135168 B)
  float* bias1 = (float*)(ws + 135168);   // 160 f32
  float* b1p   = (float*)(ws + 135808);   // 160 f32
  float* b2p   = (float*)(ws + 136448);   // 160 f32
  // contiguous packed-weight sequence (stage chunks index off P1), 1KB-aligned:
  unsigned short* P1 = (unsigned short*)(ws + 137216);  // 81920 u16 (160KB)
  unsigned short* P2 = (unsigned short*)(ws + 301056);  // 25600 u16 (50KB)
  unsigned short* P3 = (unsigned short*)(ws + 352256);  // 25600 u16 (50KB)
  unsigned short* P4 = (unsigned short*)(ws + 403456);  // 40960 u16 (80KB)

  hipLaunchKernelGGL(kP, dim3(133), dim3(256), 0, stream,
                     W0, Wu, Wm, bm, bu, b0, b1, b2, Wc, bias1, b1p, b2p);
  hipLaunchKernelGGL(kC, dim3(680), dim3(256), 0, stream,
                     W0, Wc, W1, W2, W3, P1, P2, P3, P4);
  hipLaunchKernelGGL(kD, dim3(1024), dim3(256), 53248, stream,
                     signal, comp, P1, bias1, b1p, b2p, b3, (float*)d_out);
}

// Round 2
// 199.519 us; speedup vs baseline: 1.5737x; 1.5737x over previous
//
#include <hip/hip_runtime.h>
#include <hip/hip_bf16.h>

// PointProp for MI355X (gfx950) — R6.
//   kP: prep (Wc = W0r@Wu@Wm folded; bias chain)     kC: pack weights (bf16)
//   kD: FUSED comp-sum + 4-layer MLP. R5's monolithic register comp-sum was
//       latency-bound (1 load/lane in flight, VGPR-starved at 84). R6 spreads
//       the comp-sum across the 8 pass-1 phases: phase kk issues ALL 16 loads
//       (8 k-slices x 32B) for rows {2kk, 2kk+1} up front, runs the MFMA
//       cluster, then tree-reduces -> cs[kk]. 256B/lane in flight per phase,
//       drained by the phase barrier — comp stream rides under the MLP.
//       All non-temporal hints removed (write-amplification suspect in R5).
// Math: out = L4(relu(L3(relu(L2(relu(sig@W0s^T + csum@Wc^T + bias1))))))
// with Wc = W0r@Wu@Wm folded (linearity), H padded 132->160.

typedef float  f32x4  __attribute__((ext_vector_type(4)));
typedef __bf16 bf16x8 __attribute__((ext_vector_type(8)));
typedef unsigned int   u32x2 __attribute__((ext_vector_type(2)));
typedef unsigned short u16x8 __attribute__((ext_vector_type(8)));

__device__ __forceinline__ unsigned short f2bf(float f) {
  unsigned int u = __builtin_bit_cast(unsigned int, f);
  u += 0x7fffu + ((u >> 16) & 1u);   // RNE
  return (unsigned short)(u >> 16);
}

__device__ __forceinline__ u32x2 pack4(f32x4 v) {
  u32x2 r;
  r[0] = (unsigned)f2bf(v[0]) | ((unsigned)f2bf(v[1]) << 16);
  r[1] = (unsigned)f2bf(v[2]) | ((unsigned)f2bf(v[3]) << 16);
  return r;
}

// ---- async global->LDS (dest = wave-uniform base + lane*size) ----
__device__ __forceinline__ void gl16(const void* g, void* l) {
  __builtin_amdgcn_global_load_lds(
      (const __attribute__((address_space(1))) unsigned*)(unsigned long long)g,
      (__attribute__((address_space(3))) unsigned*)(unsigned)(unsigned long long)l,
      16, 0, 0);
}
__device__ __forceinline__ void gl4(const void* g, void* l) {
  __builtin_amdgcn_global_load_lds(
      (const __attribute__((address_space(1))) unsigned*)(unsigned long long)g,
      (__attribute__((address_space(3))) unsigned*)(unsigned)(unsigned long long)l,
      4, 0, 0);
}

// stage a 10KB chunk: 2x16B issues (8KB) + 2x4B issues (2KB)
__device__ __forceinline__ void stage10k(const char* src, char* dst,
                                         int wave, int lane) {
  const char* g0 = src + wave * 1024 + lane * 16;
  char* l0 = dst + wave * 1024;
  gl16(g0, l0);
  gl16(g0 + 4096, l0 + 4096);
  const char* g1 = src + 8192 + wave * 256 + lane * 4;
  char* l1 = dst + 8192 + wave * 256;
  gl4(g1, l1);
  gl4(g1 + 1024, l1 + 1024);
}
// stage a 6KB chunk: 1x16B issue (4KB) + 2x4B issues (2KB)
__device__ __forceinline__ void stage6k(const char* src, char* dst,
                                        int wave, int lane) {
  gl16(src + wave * 1024 + lane * 16, dst + wave * 1024);
  const char* g1 = src + 4096 + wave * 256 + lane * 4;
  char* l1 = dst + 4096 + wave * 256;
  gl4(g1, l1);
  gl4(g1 + 1024, l1 + 1024);
}

// ---------------- Kernel P: all prep (Wc, bias1, padded biases) -------------
__global__ __launch_bounds__(256) void kP(
    const float* __restrict__ W0, const float* __restrict__ Wu,
    const float* __restrict__ Wm, const float* __restrict__ bm,
    const float* __restrict__ bu, const float* __restrict__ b0,
    const float* __restrict__ b1, const float* __restrict__ b2,
    float* __restrict__ Wc, float* __restrict__ bias1,
    float* __restrict__ b1p, float* __restrict__ b2p) {
  const int b = blockIdx.x;
  const int d = threadIdx.x;
  if (b < 132) {
    __shared__ float u[256];
    const int h = b;
    float s = 0.f;
#pragma unroll 8
    for (int i = 0; i < 256; ++i) s += W0[h * 512 + 256 + i] * Wu[i * 256 + d];
    u[d] = s;
    __syncthreads();
    float s2 = 0.f;
#pragma unroll 8
    for (int j = 0; j < 256; ++j) s2 += u[j] * Wm[j * 256 + d];
    Wc[h * 256 + d] = s2;
  } else {
    __shared__ float bml[256];
    __shared__ float rbl[256];
    bml[d] = bm[d];
    __syncthreads();
    {
      const f32x4* wr = (const f32x4*)(Wu + d * 256);
      const f32x4* bm4 = (const f32x4*)bml;
      float s = 0.f;
#pragma unroll 8
      for (int i = 0; i < 64; ++i) {
        f32x4 w = wr[i], v = bm4[i];
        s += w[0] * v[0] + w[1] * v[1] + w[2] * v[2] + w[3] * v[3];
      }
      rbl[d] = 8.f * s + bu[d];
    }
    __syncthreads();
    if (d < 160) {
      float v = 0.f;
      if (d < 132) {
        float s = 0.f;
#pragma unroll 8
        for (int j = 0; j < 256; ++j) s += W0[d * 512 + 256 + j] * rbl[j];
        v = b0[d] + s;
      }
      bias1[d] = v;
      b1p[d] = (d < 132) ? b1[d] : 0.f;
      b2p[d] = (d < 132) ? b2[d] : 0.f;
    }
  }
}

// ---------------- Kernel C: pack weights to MFMA B-frag order (bf16) --------
// Chunk (kk,nt) = 1024B: lane l holds B[kk*32+(l>>4)*8+j][nt*16+(l&15)], j=0..7.
// L1: K=512,N=160; L2/L3: 160x160; L4: 160x256. P1..P4 CONTIGUOUS in ws.
__global__ __launch_bounds__(256) void kC(
    const float* __restrict__ W0, const float* __restrict__ Wc,
    const float* __restrict__ W1, const float* __restrict__ W2,
    const float* __restrict__ W3,
    unsigned short* __restrict__ P1, unsigned short* __restrict__ P2,
    unsigned short* __restrict__ P3, unsigned short* __restrict__ P4) {
  int e = blockIdx.x * 256 + threadIdx.x;
  if (e >= 174080) return;
  unsigned short* dst; int NT, rel, mode;
  if (e < 81920)       { dst = P1; NT = 10; rel = e;          mode = 0; }
  else if (e < 107520) { dst = P2; NT = 10; rel = e - 81920;  mode = 1; }
  else if (e < 133120) { dst = P3; NT = 10; rel = e - 107520; mode = 2; }
  else                 { dst = P4; NT = 16; rel = e - 133120; mode = 3; }
  int chunk = rel >> 9, q = rel & 511;
  int lane = q >> 3, j = q & 7;
  int kk = chunk / NT, nt = chunk - kk * NT;
  int k = kk * 32 + (lane >> 4) * 8 + j;
  int n = nt * 16 + (lane & 15);
  float v = 0.f;
  if (mode == 0) {
    if (n < 132) v = (k < 256) ? W0[n * 512 + k] : Wc[n * 256 + (k - 256)];
  } else if (mode == 1) {
    if (n < 132 && k < 132) v = W1[n * 132 + k];
  } else if (mode == 2) {
    if (n < 132 && k < 132) v = W2[n * 132 + k];
  } else {
    if (k < 132) v = W3[n * 132 + k];
  }
  dst[rel] = f2bf(v);
}

// ---------------- Kernel D: fused comp-sum + 4-layer MLP --------------------
// grid 1024 x 256; wave owns 16 rows. LDS 53248B: 4 per-wave act tiles
// [16 rows][512B] XOR-swizzled (32KB) + weight dbuf 2x10KB.
// Pass-1 phase kk additionally streams comp rows {2kk, 2kk+1}: 16 independent
// 16B loads issued before the MFMA cluster, tree-reduced after -> cs[kk].
__global__ __launch_bounds__(256, 3) void kD(
    const float* __restrict__ signal, const float* __restrict__ comp,
    const unsigned short* __restrict__ Pseq,
    const float* __restrict__ bias1, const float* __restrict__ b1p,
    const float* __restrict__ b2p, const float* __restrict__ b3,
    float* __restrict__ out) {
  extern __shared__ char lds[];
  const int tid = threadIdx.x;
  const int wave = tid >> 6;
  const int lane = tid & 63;
  const int lhalf = lane >> 4;
  const int l16 = lane & 15;
  char* act = lds + wave * 8192;
  char* wbA = lds + 32768;
  char* wbB = lds + 32768 + 10240;
  const char* Pb = (const char*)Pseq;
  const int row0 = ((int)blockIdx.x * 4 + wave) * 16;
  const int asw = (l16 & 7) << 4;

  // ---- signal: load 16 rows f32, pack -> act tile (cols 0..255 bf16) ----
  {
    f32x4 sg[16];
    const f32x4* sp = (const f32x4*)signal;
#pragma unroll
    for (int r = 0; r < 16; ++r) sg[r] = sp[(size_t)(row0 + r) * 64 + lane];
#pragma unroll
    for (int r = 0; r < 16; ++r)
      *(u32x2*)(act + r * 512 + ((lane * 8) ^ ((r & 7) << 4))) = pack4(sg[r]);
  }

  stage10k(Pb, wbA, wave, lane);           // L1 chunk 0 -> buf0
  __syncthreads();

  const int r2 = lane >> 5, c32 = lane & 31;
  const f32x4* cp = (const f32x4*)comp;
  u16x8 cs[8];

  f32x4 acc[10];
#pragma unroll
  for (int i = 0; i < 10; ++i) acc[i] = f32x4{0.f, 0.f, 0.f, 0.f};

  // ---- layer 1 pass 1 (signal half), chunks 0..7 + comp-sum rows 2kk..2kk+1
#pragma unroll
  for (int kk = 0; kk < 8; ++kk) {
    stage10k(Pb + (kk + 1) * 10240, (((kk + 1) & 1) ? wbB : wbA), wave, lane);
    // issue this phase's comp loads (16 x 16B, independent)
    f32x4 t[16];
    {
      const size_t rbase = (size_t)(row0 + 2 * kk + r2) * 64 + c32 * 2;
#pragma unroll
      for (int k = 0; k < 8; ++k) {
        t[2 * k]     = cp[(size_t)k * 4194304u + rbase];
        t[2 * k + 1] = cp[(size_t)k * 4194304u + rbase + 1];
      }
    }
    char* wb = (kk & 1) ? wbB : wbA;
    bf16x8 af = *(const bf16x8*)(act + l16 * 512 + ((kk * 64 + lhalf * 16) ^ asw));
#pragma unroll
    for (int nt = 0; nt < 10; ++nt)
      acc[nt] = __builtin_amdgcn_mfma_f32_16x16x32_bf16(
          af, *(const bf16x8*)(wb + nt * 1024 + lane * 16), acc[nt], 0, 0, 0);
    // reduce comp slices -> cs[kk] (loads had the MFMA cluster to land)
    {
      f32x4 s0 = (t[0] + t[2]) + (t[4] + t[6]);
      s0 = s0 + ((t[8] + t[10]) + (t[12] + t[14]));
      f32x4 s1 = (t[1] + t[3]) + (t[5] + t[7]);
      s1 = s1 + ((t[9] + t[11]) + (t[13] + t[15]));
      u16x8 v;
      v[0] = f2bf(s0[0]); v[1] = f2bf(s0[1]);
      v[2] = f2bf(s0[2]); v[3] = f2bf(s0[3]);
      v[4] = f2bf(s1[0]); v[5] = f2bf(s1[1]);
      v[6] = f2bf(s1[2]); v[7] = f2bf(s1[3]);
      cs[kk] = v;
    }
    __syncthreads();
  }

  // overwrite act tile with comp-sum (wave-local)
  asm volatile("" ::: "memory");
#pragma unroll
  for (int j = 0; j < 8; ++j) {
    const int rw = 2 * j + r2;
    *(u16x8*)(act + rw * 512 + ((c32 * 16) ^ ((rw & 7) << 4))) = cs[j];
  }
  asm volatile("" ::: "memory");

  // ---- layer 1 pass 2 (comp-sum half), chunks 8..15 ----
#pragma unroll
  for (int kk = 8; kk < 16; ++kk) {
    if (kk < 15)
      stage10k(Pb + (kk + 1) * 10240, (((kk + 1) & 1) ? wbB : wbA), wave, lane);
    else
      stage10k(Pb + 163840, wbA, wave, lane);          // L2 chunk0 (c=16, buf0)
    char* wb = (kk & 1) ? wbB : wbA;
    bf16x8 af =
        *(const bf16x8*)(act + l16 * 512 + (((kk - 8) * 64 + lhalf * 16) ^ asw));
#pragma unroll
    for (int nt = 0; nt < 10; ++nt)
      acc[nt] = __builtin_amdgcn_mfma_f32_16x16x32_bf16(
          af, *(const bf16x8*)(wb + nt * 1024 + lane * 16), acc[nt], 0, 0, 0);
    __syncthreads();
  }

  // bias + relu -> act
  {
    float bv[10];
#pragma unroll
    for (int nt = 0; nt < 10; ++nt) bv[nt] = bias1[nt * 16 + l16];
    asm volatile("" ::: "memory");
#pragma unroll
    for (int nt = 0; nt < 10; ++nt) {
#pragma unroll
      for (int r = 0; r < 4; ++r) {
        const int row = lhalf * 4 + r;
        float v = fmaxf(acc[nt][r] + bv[nt], 0.f);
        *(unsigned short*)(act + row * 512 +
                           (((nt * 16 + l16) * 2) ^ ((row & 7) << 4))) = f2bf(v);
      }
    }
    asm volatile("" ::: "memory");
  }

  // ---- hidden layers (L=0: W1 @ Pb+163840; L=1: W2 @ Pb+215040) ----
#pragma unroll
  for (int L = 0; L < 2; ++L) {
    const char* hb = Pb + (L ? 215040 : 163840);
    const float* hbias = L ? b2p : b1p;
#pragma unroll
    for (int i = 0; i < 10; ++i) acc[i] = f32x4{0.f, 0.f, 0.f, 0.f};
#pragma unroll
    for (int kk = 0; kk < 5; ++kk) {
      const char* nsrc = (kk < 4) ? (hb + (kk + 1) * 10240)
                                  : (L ? (Pb + 266240) : (Pb + 215040));
      stage10k(nsrc, (((kk + L + 1) & 1) ? wbB : wbA), wave, lane);
      char* wb = ((kk + L) & 1) ? wbB : wbA;
      bf16x8 af =
          *(const bf16x8*)(act + l16 * 512 + ((kk * 64 + lhalf * 16) ^ asw));
#pragma unroll
      for (int nt = 0; nt < 10; ++nt)
        acc[nt] = __builtin_amdgcn_mfma_f32_16x16x32_bf16(
            af, *(const bf16x8*)(wb + nt * 1024 + lane * 16), acc[nt], 0, 0, 0);
      __syncthreads();
    }
    float bv[10];
#pragma unroll
    for (int nt = 0; nt < 10; ++nt) bv[nt] = hbias[nt * 16 + l16];
    asm volatile("" ::: "memory");
#pragma unroll
    for (int nt = 0; nt < 10; ++nt) {
#pragma unroll
      for (int r = 0; r < 4; ++r) {
        const int row = lhalf * 4 + r;
        float v = fmaxf(acc[nt][r] + bv[nt], 0.f);
        *(unsigned short*)(act + row * 512 +
                           (((nt * 16 + l16) * 2) ^ ((row & 7) << 4))) = f2bf(v);
      }
    }
    asm volatile("" ::: "memory");
  }

  // ---- layer 4: chunks (kk,h0)=nt0..9 @buf0, (kk,h1)=nt10..15 @buf1 ----
  f32x4 a4[16];
#pragma unroll
  for (int i = 0; i < 16; ++i) a4[i] = f32x4{0.f, 0.f, 0.f, 0.f};
  const char* P4b = Pb + 266240;
#pragma unroll
  for (int kk = 0; kk < 5; ++kk) {
    // h0 phase
    stage6k(P4b + kk * 16384 + 10240, wbB, wave, lane);
    bf16x8 af =
        *(const bf16x8*)(act + l16 * 512 + ((kk * 64 + lhalf * 16) ^ asw));
#pragma unroll
    for (int nt = 0; nt < 10; ++nt)
      a4[nt] = __builtin_amdgcn_mfma_f32_16x16x32_bf16(
          af, *(const bf16x8*)(wbA + nt * 1024 + lane * 16), a4[nt], 0, 0, 0);
    __syncthreads();
    // h1 phase
    if (kk < 4) stage10k(P4b + (kk + 1) * 16384, wbA, wave, lane);
#pragma unroll
    for (int nt = 10; nt < 16; ++nt)
      a4[nt] = __builtin_amdgcn_mfma_f32_16x16x32_bf16(
          af, *(const bf16x8*)(wbB + (nt - 10) * 1024 + lane * 16), a4[nt], 0, 0, 0);
    __syncthreads();
  }

  // ---- store ----
  float bv[16];
#pragma unroll
  for (int nt = 0; nt < 16; ++nt) bv[nt] = b3[nt * 16 + l16];
  float* op = out + (size_t)(row0 + lhalf * 4) * 256 + l16;
#pragma unroll
  for (int nt = 0; nt < 16; ++nt) {
#pragma unroll
    for (int r = 0; r < 4; ++r)
      op[(size_t)r * 256 + nt * 16] = a4[nt][r] + bv[nt];
  }
}

// ---------------- launcher ----------------
extern "C" void kernel_launch(void* const* d_in, const int* in_sizes, int n_in,
                              void* d_out, int out_size, void* d_ws, size_t ws_size,
                              hipStream_t stream) {
  const float* signal = (const float*)d_in[0];
  const float* comp   = (const float*)d_in[1];
  const float* Wm = (const float*)d_in[2];
  const float* bm = (const float*)d_in[3];
  const float* Wu = (const float*)d_in[4];
  const float* bu = (const float*)d_in[5];
  const float* W0 = (const float*)d_in[6];
  const float* b0 = (const float*)d_in[7];
  const float* W1 = (const float*)d_in[8];
  const float* b1 = (const float*)d_in[9];
  const float* W2 = (const float*)d_in[10];
  const float* b2 = (const float*)d_in[11];
  const float* W3 = (const float*)d_in[12];
  const float* b3 = (const float*)d_in[13];

  char* ws = (char*)d_ws;
  float* Wc    = (float*)(ws + 0);        // 33792 f32 (135168 B)
  float* bias1 = (float*)(ws + 135168);   // 160 f32
  float* b1p   = (float*)(ws + 135808);   // 160 f32
  float* b2p   = (float*)(ws + 136448);   // 160 f32
  // contiguous packed-weight sequence (stage chunks index off P1), 1KB-aligned:
  unsigned short* P1 = (unsigned short*)(ws + 137216);  // 81920 u16 (160KB)
  unsigned short* P2 = (unsigned short*)(ws + 301056);  // 25600 u16 (50KB)
  unsigned short* P3 = (unsigned short*)(ws + 352256);  // 25600 u16 (50KB)
  unsigned short* P4 = (unsigned short*)(ws + 403456);  // 40960 u16 (80KB)

  hipLaunchKernelGGL(kP, dim3(133), dim3(256), 0, stream,
                     W0, Wu, Wm, bm, bu, b0, b1, b2, Wc, bias1, b1p, b2p);
  hipLaunchKernelGGL(kC, dim3(680), dim3(256), 0, stream,
                     W0, Wc, W1, W2, W3, P1, P2, P3, P4);
  hipLaunchKernelGGL(kD, dim3(1024), dim3(256), 53248, stream,
                     signal, comp, P1, bias1, b1p, b2p, b3, (float*)d_out);
}